// Round 2
// baseline (587.055 us; speedup 1.0000x reference)
//
#include <hip/hip_runtime.h>
#include <math.h>

#define PB 32      // preds per batch
#define GB 24      // gt instances per batch
#define NBATCH 2
#define SX_OFF   0
#define SSIG_OFF (NBATCH*PB*GB)
#define SNEG_OFF (2*NBATCH*PB*GB)
#define SFOC_OFF (3*NBATCH*PB*GB)
#define CNT_OFF  (4*NBATCH*PB*GB)
#define STRIDE   (4*NBATCH*PB*GB + NBATCH*GB)   // 6144 + 48 = 6192
#define SEGS 8

// ---------------- K1: per-block privatized accumulation of sufficient stats ----------------
__global__ __launch_bounds__(256) void k_accum(
    const float* __restrict__ logits, const int* __restrict__ vb,
    const int* __restrict__ gi, float* __restrict__ partials, int NV)
{
    __shared__ float acc[4][NBATCH][PB][GB];   // S_x, S_sig, S_neg, S_foc
    __shared__ float scnt[NBATCH][GB];
    float* lf = &acc[0][0][0][0];
    for (int j = threadIdx.x; j < 4*NBATCH*PB*GB; j += blockDim.x) lf[j] = 0.f;
    for (int j = threadIdx.x; j < NBATCH*GB; j += blockDim.x) (&scnt[0][0])[j] = 0.f;
    __syncthreads();

    int stride = gridDim.x * blockDim.x;
    for (int v = blockIdx.x * blockDim.x + threadIdx.x; v < NV; v += stride) {
        int b  = vb[v];
        int il = gi[v] - GB * b;               // local instance 0..23
        const float4* row = (const float4*)(logits + (size_t)v * (NBATCH*PB) + PB * b);
        atomicAdd(&scnt[b][il], 1.0f);
        float* a0 = &acc[0][b][0][il];
        float* a1 = &acc[1][b][0][il];
        float* a2 = &acc[2][b][0][il];
        float* a3 = &acc[3][b][0][il];
        #pragma unroll
        for (int k = 0; k < PB/4; ++k) {
            float4 q = row[k];
            float xs[4] = {q.x, q.y, q.z, q.w};
            #pragma unroll
            for (int e = 0; e < 4; ++e) {
                int p = 4*k + e;
                float x   = xs[e];
                float ax  = fabsf(x);
                float ex  = __expf(-ax);
                float neg = fmaxf(x, 0.f) + __logf(1.f + ex);   // softplus(x)
                float r   = __builtin_amdgcn_rcpf(1.f + ex);
                float sig = (x >= 0.f) ? r : ex * r;            // sigmoid(x)
                float foc = neg * sig * sig;                    // softplus*sig^2 (0.75 applied later)
                atomicAdd(a0 + p*GB, x);
                atomicAdd(a1 + p*GB, sig);
                atomicAdd(a2 + p*GB, neg);
                atomicAdd(a3 + p*GB, foc);
            }
        }
    }
    __syncthreads();
    float* outp = partials + (size_t)blockIdx.x * STRIDE;
    for (int j = threadIdx.x; j < 4*NBATCH*PB*GB; j += blockDim.x) outp[j] = lf[j];
    for (int j = threadIdx.x; j < NBATCH*GB; j += blockDim.x)
        outp[4*NBATCH*PB*GB + j] = (&scnt[0][0])[j];
}

// ---------------- K2: deterministic partial tree-reduce across blocks ----------------
__global__ __launch_bounds__(256) void k_reduce(
    const float* __restrict__ partials, float* __restrict__ tmp,
    int nblocks, int seg_size)
{
    int j = blockIdx.x * blockDim.x + threadIdx.x;
    if (j >= STRIDE) return;
    int seg = blockIdx.y;
    int lo = seg * seg_size;
    int hi = lo + seg_size; if (hi > nblocks) hi = nblocks;
    float s = 0.f;
    for (int bl = lo; bl < hi; ++bl) s += partials[(size_t)bl * STRIDE + j];
    tmp[(size_t)seg * STRIDE + j] = s;
}

// ---------------- K3: cost build + JV Hungarian (wave-parallel columns) + losses ----------------
__global__ __launch_bounds__(128) void k_final(
    const float* __restrict__ tmp, int nseg, float* __restrict__ outp)
{
    __shared__ float sx[NBATCH][PB][GB];
    __shared__ float ssig[NBATCH][PB][GB];
    __shared__ float tneg[NBATCH][PB], tsig[NBATCH][PB], tfoc[NBATCH][PB];
    __shared__ float cnt[NBATCH][GB];
    __shared__ float nvbs[NBATCH];
    __shared__ double Ct[NBATCH][GB][PB];     // transposed cost: rows=instances, cols=preds
    __shared__ double uarr[NBATCH][GB+1];
    __shared__ int    parr[NBATCH][PB+1];
    __shared__ int    wayarr[NBATCH][PB+1];
    __shared__ double bres[NBATCH][3];        // bce, dice, unmatched

    int tid = threadIdx.x;
    auto tot = [&](int j) {
        float s = 0.f;
        for (int sgi = 0; sgi < nseg; ++sgi) s += tmp[(size_t)sgi * STRIDE + j];
        return s;
    };

    // stage 1: load S_x, S_sig, cnt
    for (int j = tid; j < NBATCH*PB*GB; j += blockDim.x) (&sx[0][0][0])[j]   = tot(SX_OFF + j);
    for (int j = tid; j < NBATCH*PB*GB; j += blockDim.x) (&ssig[0][0][0])[j] = tot(SSIG_OFF + j);
    for (int j = tid; j < NBATCH*GB; j += blockDim.x)    (&cnt[0][0])[j]     = tot(CNT_OFF + j);
    __syncthreads();

    // stage 2: per-pred totals (row sums), per-batch voxel counts
    for (int q = tid; q < NBATCH*PB; q += blockDim.x) {
        float a = 0.f, c = 0.f, s = 0.f;
        for (int i2 = 0; i2 < GB; ++i2) {
            a += tot(SNEG_OFF + q*GB + i2);
            c += tot(SFOC_OFF + q*GB + i2);
            s += (&ssig[0][0][0])[q*GB + i2];
        }
        (&tneg[0][0])[q] = a; (&tfoc[0][0])[q] = c; (&tsig[0][0])[q] = s;
    }
    if (tid < NBATCH) {
        float s = 0.f;
        for (int i2 = 0; i2 < GB; ++i2) s += cnt[tid][i2];
        nvbs[tid] = s;
    }
    __syncthreads();

    // stage 3: cost matrix (L_B=2, L_D=1)
    for (int idx = tid; idx < NBATCH*GB*PB; idx += blockDim.x) {
        int b  = idx / (GB*PB);
        int r  = idx % (GB*PB);
        int i2 = r / PB;
        int j2 = r % PB;
        float nv = nvbs[b];
        float bceC  = 2.0f * (tneg[b][j2] - sx[b][j2][i2]) / nv;                       // L_B=2
        float diceC = 1.0f * (1.f - (2.f*ssig[b][j2][i2] + 1.f) /
                                    (tsig[b][j2] + cnt[b][i2] + 1.f));                 // L_D=1
        Ct[b][i2][j2] = (double)(bceC + diceC);
    }
    __syncthreads();

    // stage 4: per-wave JV Hungarian (wave b handles batch b; lane = column j)
    int wave = tid >> 6;
    int lane = tid & 63;
    if (wave < NBATCH) {
        int b = wave;
        const int n = GB, m = PB;
        if (lane <= n) uarr[b][lane] = 0.0;
        if (lane <= m) parr[b][lane] = 0;
        int j = lane;
        bool valid = (j >= 1 && j <= m);
        double vj = 0.0;

        for (int i = 1; i <= n; ++i) {
            if (lane == 0) parr[b][0] = i;
            int j0 = 0;
            double minvj = 1e300;
            bool usedj = false;
            for (int guard = 0; guard < 4*PB; ++guard) {
                if (j == j0) usedj = true;
                int i0 = parr[b][j0];
                double u0 = uarr[b][i0];
                if (valid && !usedj) {
                    double cur = Ct[b][i0-1][j-1] - u0 - vj;
                    if (cur < minvj) { minvj = cur; wayarr[b][j] = j0; }
                }
                double bestv = (valid && !usedj) ? minvj : 1e300;
                int bestj = j;
                #pragma unroll
                for (int off = 32; off >= 1; off >>= 1) {
                    double ov = __shfl_xor(bestv, off);
                    int    oj = __shfl_xor(bestj, off);
                    if (ov < bestv || (ov == bestv && oj < bestj)) { bestv = ov; bestj = oj; }
                }
                double delta = bestv;
                if (j <= m) {
                    if (usedj) {
                        int pj = parr[b][j];        // distinct rows per used column
                        uarr[b][pj] += delta;
                        vj -= delta;
                    } else if (valid) {
                        minvj -= delta;
                    }
                }
                j0 = bestj;
                if (parr[b][j0] == 0) break;
            }
            // augment (all lanes lockstep, identical writes)
            int jj = j0;
            for (int guard = 0; guard < 2*PB && jj; ++guard) {
                int j1 = wayarr[b][jj];
                parr[b][jj] = parr[b][j1];
                jj = j1;
            }
        }

        // per-batch loss components
        double nvbd = (double)nvbs[b];
        double myb = 0.0, myd = 0.0, myf = 0.0, myu = 0.0;
        if (valid) {
            int pj = parr[b][j];
            int p = j - 1;
            if (pj > 0) {
                int ii = pj - 1;
                myb = ((double)tneg[b][p] - (double)sx[b][p][ii]) / nvbd;
                myd = 1.0 - (2.0*(double)ssig[b][p][ii] + 1.0) /
                            ((double)tsig[b][p] + (double)cnt[b][ii] + 1.0);
            } else {
                myf = (double)tfoc[b][p];
                myu = 1.0;
            }
        }
        #pragma unroll
        for (int off = 32; off >= 1; off >>= 1) {
            myb += __shfl_xor(myb, off);
            myd += __shfl_xor(myd, off);
            myf += __shfl_xor(myf, off);
            myu += __shfl_xor(myu, off);
        }
        if (lane == 0) {
            double G = (double)GB;
            double bce  = 2.0 * myb / G;                                  // L_B = 2
            double dice = 1.0 * myd / G;                                  // L_D = 1
            double unm  = (myu > 0.0) ? 7.0 * 0.75 * myf / (myu * nvbd)   // L_U, alpha
                                      : 0.0;
            bres[b][0] = bce; bres[b][1] = dice; bres[b][2] = unm;
        }
    }
    __syncthreads();

    // stage 5: combine batches
    if (tid == 0) {
        double L[5] = {0,0,0,0,0};
        for (int b = 0; b < NBATCH; ++b) {
            double bce = bres[b][0], dice = bres[b][1], unm = bres[b][2];
            double matched = bce + dice;     // L_M = 1
            double total = matched + unm;
            L[0] += total; L[1] += matched; L[2] += unm; L[3] += bce; L[4] += dice;
        }
        for (int k2 = 0; k2 < 5; ++k2) outp[k2] = (float)(L[k2] / NBATCH);
    }
}

extern "C" void kernel_launch(void* const* d_in, const int* in_sizes, int n_in,
                              void* d_out, int out_size, void* d_ws, size_t ws_size,
                              hipStream_t stream)
{
    const float* logits = (const float*)d_in[0];
    const int* vb = (const int*)d_in[1];
    const int* gi = (const int*)d_in[2];
    int NV = in_sizes[1];

    float* ws = (float*)d_ws;
    size_t avail = ws_size / sizeof(float);
    int nblocks = 512;
    if ((size_t)(nblocks + SEGS) * STRIDE > avail) {
        long cap = (long)(avail / STRIDE) - SEGS;
        nblocks = (cap < 1) ? 1 : (cap > 512 ? 512 : (int)cap);
    }
    float* partials = ws;
    float* tmp = ws + (size_t)nblocks * STRIDE;
    int seg_size = (nblocks + SEGS - 1) / SEGS;

    hipLaunchKernelGGL(k_accum, dim3(nblocks), dim3(256), 0, stream,
                       logits, vb, gi, partials, NV);
    hipLaunchKernelGGL(k_reduce, dim3((STRIDE + 255)/256, SEGS), dim3(256), 0, stream,
                       partials, tmp, nblocks, seg_size);
    hipLaunchKernelGGL(k_final, dim3(1), dim3(128), 0, stream,
                       tmp, SEGS, (float*)d_out);
}

// Round 3
// 471.119 us; speedup vs baseline: 1.2461x; 1.2461x over previous
//
#include <hip/hip_runtime.h>
#include <math.h>

#define PB 32      // preds per batch
#define GB 24      // gt instances per batch
#define ILSTR 165  // dwords per instance row in wave-private LDS (bank-spread)
#define CNT_OFF (GB*ILSTR)          // 3960
#define REGION  3984                // 3960 + 24 cnt
#define NBLK_DEF 512

// ---------------- K0: find batch boundary B0 (first index with vb==1) ----------------
__global__ __launch_bounds__(256) void k_bound(const int* __restrict__ vb, int NV, int* __restrict__ out)
{
    __shared__ int smax;
    int t = threadIdx.x;
    if (t == 0) smax = 0;
    __syncthreads();
    int lo = 0, len = NV;
    while (len > 1) {
        int step = (len + 255) >> 8;
        int pos = lo + t * step;
        if (pos < lo + len && pos < NV && vb[pos] == 0) atomicMax(&smax, pos);
        __syncthreads();
        lo = smax; len = step;
        __syncthreads();
    }
    if (t == 0) out[0] = lo + 1;
}

// ---------------- K1: wave-private LDS accumulation, no colliding atomics ----------------
__global__ __launch_bounds__(256) void k_accum(
    const float* __restrict__ logits, const int* __restrict__ gi,
    const int* __restrict__ b0ptr, float* __restrict__ partials,
    int NV, int half)
{
    __shared__ float lds[4 * REGION];    // 63.7 KB: one region per wave
    int tid = threadIdx.x;
    for (int j = tid; j < 4 * REGION; j += 256) lds[j] = 0.f;
    __syncthreads();

    const int B0 = b0ptr[0];
    int wave = tid >> 6, lane = tid & 63;
    int vi = lane >> 3;                  // voxel-in-group 0..7
    int c0 = (lane & 7) * 4;             // 4 columns per lane
    int b = (blockIdx.x >= half) ? 1 : 0;
    int vstart = b ? B0 : 0;
    int vend   = b ? NV : B0;
    int nw = half * 4;
    int wid = (blockIdx.x - b * half) * 4 + wave;
    int nvb = vend - vstart;
    int chunk = (nvb + nw - 1) / nw;
    int v0 = vstart + wid * chunk;
    int v1 = v0 + chunk; if (v1 > vend) v1 = vend;

    float* wl = lds + wave * REGION;
    const float* xb = logits + 32 * b + c0;
    int gofs = -24 * b;

    #pragma unroll 4
    for (int v = v0; v < v1; v += 8) {
        int vl = v + vi;
        bool act = (vl < v1);
        if (act) {
            float4 xq = *(const float4*)(xb + (size_t)vl * 64);
            int il = gi[vl] + gofs;
            float* cell = wl + il * ILSTR + c0 * 5;
            float xs[4] = {xq.x, xq.y, xq.z, xq.w};
            #pragma unroll
            for (int e = 0; e < 4; ++e) {
                float x  = xs[e];
                float ax = fabsf(x);
                float ex = __expf(-ax);
                float neg = fmaxf(x, 0.f) + __logf(1.f + ex);    // softplus(x)
                float r  = __builtin_amdgcn_rcpf(1.f + ex);
                float sig = (x >= 0.f) ? r : ex * r;             // sigmoid(x)
                atomicAdd(cell + e*5 + 0, x);
                atomicAdd(cell + e*5 + 1, sig);
                atomicAdd(cell + e*5 + 2, neg);
                atomicAdd(cell + e*5 + 3, neg * sig * sig);
            }
            if ((lane & 7) == 0) atomicAdd(wl + CNT_OFF + il, 1.f);
        }
    }
    __syncthreads();
    // deterministic 4-wave reduce
    float* op = partials + (size_t)blockIdx.x * REGION;
    for (int j = tid; j < REGION; j += 256)
        op[j] = lds[j] + lds[REGION + j] + lds[2*REGION + j] + lds[3*REGION + j];
}

// ---------------- K2: deterministic block-partial tree reduce ----------------
__global__ __launch_bounds__(256) void k_reduce(
    const float* __restrict__ partials, float* __restrict__ tmp, int half)
{
    int j = blockIdx.x * 256 + threadIdx.x;
    if (j >= REGION) return;
    int y = blockIdx.y;           // 0..7 -> (batch, seg)
    int b = y >> 2, seg = y & 3;
    int segsz = (half + 3) >> 2;
    int lo = seg * segsz, hi = lo + segsz; if (hi > half) hi = half;
    const float* base = partials + (size_t)(b * half) * REGION + j;
    float s = 0.f;
    for (int k = lo; k < hi; ++k) s += base[(size_t)k * REGION];
    tmp[(size_t)y * REGION + j] = s;
}

// ---------------- K3: LDS-staged cost build + JV Hungarian + losses ----------------
__global__ __launch_bounds__(256) void k_final(
    const float* __restrict__ tmp, float* __restrict__ outp)
{
    __shared__ float fs[2][REGION];
    __shared__ float tneg[2][PB], tsig[2][PB], tfoc[2][PB];
    __shared__ float nvbs[2];
    __shared__ double Ct[2][GB][PB];
    __shared__ double uarr[2][GB+1];
    __shared__ int    parr[2][PB+1];
    __shared__ int    wayarr[2][PB+1];
    __shared__ double bres[2][3];

    int tid = threadIdx.x;
    for (int j = tid; j < REGION; j += 256) {
        fs[0][j] = tmp[j] + tmp[REGION+j] + tmp[2*REGION+j] + tmp[3*REGION+j];
        fs[1][j] = tmp[4*REGION+j] + tmp[5*REGION+j] + tmp[6*REGION+j] + tmp[7*REGION+j];
    }
    __syncthreads();

    if (tid < 64) {
        int b = tid >> 5, p = tid & 31;
        float tn = 0.f, ts = 0.f, tf = 0.f;
        for (int i = 0; i < GB; ++i) {
            const float* cell = &fs[b][i*ILSTR + p*5];
            ts += cell[1]; tn += cell[2]; tf += cell[3];
        }
        tneg[b][p] = tn; tsig[b][p] = ts; tfoc[b][p] = tf;
    }
    if (tid >= 64 && tid < 66) {
        int b = tid - 64; float s = 0.f;
        for (int i = 0; i < GB; ++i) s += fs[b][CNT_OFF + i];
        nvbs[b] = s;
    }
    __syncthreads();

    // cost matrix (L_B=2, L_D=1), float math as reference then double for JV
    for (int idx = tid; idx < 2*GB*PB; idx += 256) {
        int b = idx / (GB*PB), r = idx % (GB*PB), i = r / PB, j = r % PB;
        float nv = nvbs[b];
        const float* cell = &fs[b][i*ILSTR + j*5];
        float bceC  = 2.0f * (tneg[b][j] - cell[0]) / nv;
        float diceC = 1.0f - (2.f*cell[1] + 1.f) / (tsig[b][j] + fs[b][CNT_OFF+i] + 1.f);
        Ct[b][i][j] = (double)(bceC + diceC);
    }
    __syncthreads();

    // JV Hungarian: wave b handles batch b; lane = column j
    int wave = tid >> 6;
    int lane = tid & 63;
    if (wave < 2) {
        int b = wave;
        const int n = GB, m = PB;
        if (lane <= n) uarr[b][lane] = 0.0;
        if (lane <= m) parr[b][lane] = 0;
        int j = lane;
        bool valid = (j >= 1 && j <= m);
        double vj = 0.0;

        for (int i = 1; i <= n; ++i) {
            if (lane == 0) parr[b][0] = i;
            int j0 = 0;
            double minvj = 1e300;
            bool usedj = false;
            for (int guard = 0; guard < 4*PB; ++guard) {
                if (j == j0) usedj = true;
                int i0 = parr[b][j0];
                double u0 = uarr[b][i0];
                if (valid && !usedj) {
                    double cur = Ct[b][i0-1][j-1] - u0 - vj;
                    if (cur < minvj) { minvj = cur; wayarr[b][j] = j0; }
                }
                double bestv = (valid && !usedj) ? minvj : 1e300;
                int bestj = j;
                #pragma unroll
                for (int off = 32; off >= 1; off >>= 1) {
                    double ov = __shfl_xor(bestv, off);
                    int    oj = __shfl_xor(bestj, off);
                    if (ov < bestv || (ov == bestv && oj < bestj)) { bestv = ov; bestj = oj; }
                }
                double delta = bestv;
                if (j <= m) {
                    if (usedj) {
                        int pj = parr[b][j];
                        uarr[b][pj] += delta;
                        vj -= delta;
                    } else if (valid) {
                        minvj -= delta;
                    }
                }
                j0 = bestj;
                if (parr[b][j0] == 0) break;
            }
            int jj = j0;
            for (int guard = 0; guard < 2*PB && jj; ++guard) {
                int j1 = wayarr[b][jj];
                parr[b][jj] = parr[b][j1];
                jj = j1;
            }
        }

        // per-batch loss components
        double nvbd = (double)nvbs[b];
        double myb = 0.0, myd = 0.0, myf = 0.0, myu = 0.0;
        if (valid) {
            int pj = parr[b][j];
            int p = j - 1;
            if (pj > 0) {
                int ii = pj - 1;
                const float* cell = &fs[b][ii*ILSTR + p*5];
                myb = ((double)tneg[b][p] - (double)cell[0]) / nvbd;
                myd = 1.0 - (2.0*(double)cell[1] + 1.0) /
                            ((double)tsig[b][p] + (double)fs[b][CNT_OFF+ii] + 1.0);
            } else {
                myf = (double)tfoc[b][p];
                myu = 1.0;
            }
        }
        #pragma unroll
        for (int off = 32; off >= 1; off >>= 1) {
            myb += __shfl_xor(myb, off);
            myd += __shfl_xor(myd, off);
            myf += __shfl_xor(myf, off);
            myu += __shfl_xor(myu, off);
        }
        if (lane == 0) {
            double G = (double)GB;
            double bce  = 2.0 * myb / G;                                  // L_B = 2
            double dice = 1.0 * myd / G;                                  // L_D = 1
            double unm  = (myu > 0.0) ? 7.0 * 0.75 * myf / (myu * nvbd)   // L_U, alpha
                                      : 0.0;
            bres[b][0] = bce; bres[b][1] = dice; bres[b][2] = unm;
        }
    }
    __syncthreads();

    if (tid == 0) {
        double L[5] = {0,0,0,0,0};
        for (int b = 0; b < 2; ++b) {
            double bce = bres[b][0], dice = bres[b][1], unm = bres[b][2];
            double matched = bce + dice;
            double total = matched + unm;
            L[0] += total; L[1] += matched; L[2] += unm; L[3] += bce; L[4] += dice;
        }
        for (int k2 = 0; k2 < 5; ++k2) outp[k2] = (float)(L[k2] / 2.0);
    }
}

extern "C" void kernel_launch(void* const* d_in, const int* in_sizes, int n_in,
                              void* d_out, int out_size, void* d_ws, size_t ws_size,
                              hipStream_t stream)
{
    const float* logits = (const float*)d_in[0];
    const int* vb = (const int*)d_in[1];
    const int* gi = (const int*)d_in[2];
    int NV = in_sizes[1];

    float* ws = (float*)d_ws;
    size_t avail = ws_size / sizeof(float);
    int nblk = NBLK_DEF;
    while (nblk > 2 && (size_t)(64 + (size_t)(nblk + 8) * REGION) > avail) nblk -= 2;
    int half = nblk / 2;

    int*   b0ptr    = (int*)ws;                  // header
    float* partials = ws + 64;
    float* tmp      = partials + (size_t)nblk * REGION;

    hipLaunchKernelGGL(k_bound, dim3(1), dim3(256), 0, stream, vb, NV, b0ptr);
    hipLaunchKernelGGL(k_accum, dim3(nblk), dim3(256), 0, stream,
                       logits, gi, b0ptr, partials, NV, half);
    hipLaunchKernelGGL(k_reduce, dim3((REGION + 255)/256, 8), dim3(256), 0, stream,
                       partials, tmp, half);
    hipLaunchKernelGGL(k_final, dim3(1), dim3(256), 0, stream,
                       tmp, (float*)d_out);
}

// Round 4
// 333.559 us; speedup vs baseline: 1.7600x; 1.4124x over previous
//
#include <hip/hip_runtime.h>
#include <math.h>

#define PB 32      // preds per batch
#define GB 24      // gt instances per batch
#define ILS 65     // dwords per instance row (32 cols x 2 stats + 1 pad; odd -> bank spread)
#define CNT_OFF (GB*ILS)            // 1560
#define TOFF    (GB*ILS + GB)       // 1584
#define REGION  (GB*ILS + GB + 96)  // 1680: stats + cnt + T[96]
#define NBLK_DEF 768

// ---------------- K0: find batch boundary B0 (first index with vb==1) ----------------
__global__ __launch_bounds__(256) void k_bound(const int* __restrict__ vb, int NV, int* __restrict__ out)
{
    __shared__ int smax;
    int t = threadIdx.x;
    if (t == 0) smax = 0;
    __syncthreads();
    int lo = 0, len = NV;
    while (len > 1) {
        int step = (len + 255) >> 8;
        int pos = lo + t * step;
        if (pos < lo + len && pos < NV && vb[pos] == 0) atomicMax(&smax, pos);
        __syncthreads();
        lo = smax; len = step;
        __syncthreads();
    }
    if (t == 0) out[0] = lo + 1;
}

// ---------------- K1: native ds_add_f32 accumulation, T-stats in registers ----------------
__global__ __launch_bounds__(256) void k_accum(
    const float* __restrict__ logits, const int* __restrict__ gi,
    const int* __restrict__ b0ptr, float* __restrict__ partials,
    int NV, int half)
{
    __shared__ float lds[4 * (GB*ILS + GB)];   // 4 wave-private regions (25.4 KB)
    __shared__ float Tacc[96];
    int tid = threadIdx.x;
    for (int j = tid; j < 4 * (GB*ILS + GB); j += 256) lds[j] = 0.f;
    if (tid < 96) Tacc[tid] = 0.f;
    __syncthreads();

    const int B0 = b0ptr[0];
    int wave = tid >> 6, lane = tid & 63;
    int vi = lane >> 3;                  // voxel-in-group 0..7
    int c0 = (lane & 7) * 4;             // 4 owned columns
    int b = (blockIdx.x >= half) ? 1 : 0;
    int vstart = b ? B0 : 0;
    int vend   = b ? NV : B0;
    int nw = half * 4;
    int wid = (blockIdx.x - b * half) * 4 + wave;
    int nvb = vend - vstart;
    int chunk = (nvb + nw - 1) / nw;
    int v0 = vstart + wid * chunk;
    int v1 = v0 + chunk; if (v1 > vend) v1 = vend;

    float* wl = lds + wave * (GB*ILS + GB);
    const float* xb = logits + 32 * b + c0;
    int gofs = -24 * b;

    float tneg_r[4] = {0.f,0.f,0.f,0.f};
    float tsig_r[4] = {0.f,0.f,0.f,0.f};
    float tfoc_r[4] = {0.f,0.f,0.f,0.f};

    #pragma unroll 4
    for (int v = v0; v < v1; v += 8) {
        int vl = v + vi;
        if (vl < v1) {
            float4 xq = *(const float4*)(xb + (size_t)vl * 64);
            int il = gi[vl] + gofs;
            float* cell = wl + il * ILS + c0 * 2;
            float xs[4] = {xq.x, xq.y, xq.z, xq.w};
            #pragma unroll
            for (int e = 0; e < 4; ++e) {
                float x  = xs[e];
                float ax = fabsf(x);
                float ex = __expf(-ax);
                float neg = fmaxf(x, 0.f) + __logf(1.f + ex);    // softplus(x)
                float r  = __builtin_amdgcn_rcpf(1.f + ex);
                float sig = (x >= 0.f) ? r : ex * r;             // sigmoid(x)
                unsafeAtomicAdd(cell + e*2,     x);              // ds_add_f32, no return
                unsafeAtomicAdd(cell + e*2 + 1, sig);
                tneg_r[e] += neg;
                tsig_r[e] += sig;
                tfoc_r[e] += neg * sig * sig;
            }
            if ((lane & 7) == 0) unsafeAtomicAdd(wl + CNT_OFF + il, 1.f);
        }
    }
    __syncthreads();

    // reduce per-lane T registers (32 threads share each column; one-time cost)
    #pragma unroll
    for (int e = 0; e < 4; ++e) {
        int col = c0 + e;
        unsafeAtomicAdd(&Tacc[col],      tneg_r[e]);
        unsafeAtomicAdd(&Tacc[32 + col], tsig_r[e]);
        unsafeAtomicAdd(&Tacc[64 + col], tfoc_r[e]);
    }
    __syncthreads();

    // deterministic 4-wave reduce + write block partials
    float* op = partials + (size_t)blockIdx.x * REGION;
    const int WR = GB*ILS + GB;
    for (int j = tid; j < WR; j += 256)
        op[j] = lds[j] + lds[WR + j] + lds[2*WR + j] + lds[3*WR + j];
    for (int j = tid; j < 96; j += 256) op[TOFF + j] = Tacc[j];
}

// ---------------- K2: deterministic block-partial tree reduce ----------------
__global__ __launch_bounds__(256) void k_reduce(
    const float* __restrict__ partials, float* __restrict__ tmp, int half)
{
    int j = blockIdx.x * 256 + threadIdx.x;
    if (j >= REGION) return;
    int y = blockIdx.y;           // 0..7 -> (batch, seg)
    int b = y >> 2, seg = y & 3;
    int segsz = (half + 3) >> 2;
    int lo = seg * segsz, hi = lo + segsz; if (hi > half) hi = half;
    const float* base = partials + (size_t)(b * half) * REGION + j;
    float s = 0.f;
    for (int k = lo; k < hi; ++k) s += base[(size_t)k * REGION];
    tmp[(size_t)y * REGION + j] = s;
}

// ---------------- K3: LDS-staged cost build + JV Hungarian + losses ----------------
__global__ __launch_bounds__(256) void k_final(
    const float* __restrict__ tmp, float* __restrict__ outp)
{
    __shared__ float fs[2][REGION];
    __shared__ float nvbs[2];
    __shared__ double Ct[2][GB][PB];
    __shared__ double uarr[2][GB+1];
    __shared__ int    parr[2][PB+1];
    __shared__ int    wayarr[2][PB+1];
    __shared__ double bres[2][3];

    int tid = threadIdx.x;
    for (int j = tid; j < REGION; j += 256) {
        fs[0][j] = tmp[j] + tmp[REGION+j] + tmp[2*REGION+j] + tmp[3*REGION+j];
        fs[1][j] = tmp[4*REGION+j] + tmp[5*REGION+j] + tmp[6*REGION+j] + tmp[7*REGION+j];
    }
    __syncthreads();

    if (tid < 2) {
        float s = 0.f;
        for (int i = 0; i < GB; ++i) s += fs[tid][CNT_OFF + i];
        nvbs[tid] = s;
    }
    __syncthreads();

    // cost matrix (L_B=2, L_D=1), float math as reference then double for JV
    for (int idx = tid; idx < 2*GB*PB; idx += 256) {
        int b = idx / (GB*PB), r = idx % (GB*PB), i = r / PB, j = r % PB;
        float nv = nvbs[b];
        float sx   = fs[b][i*ILS + j*2];
        float ssig = fs[b][i*ILS + j*2 + 1];
        float bceC  = 2.0f * (fs[b][TOFF + j] - sx) / nv;
        float diceC = 1.0f - (2.f*ssig + 1.f) / (fs[b][TOFF + 32 + j] + fs[b][CNT_OFF + i] + 1.f);
        Ct[b][i][j] = (double)(bceC + diceC);
    }
    __syncthreads();

    // JV Hungarian: wave b handles batch b; lane = column j
    int wave = tid >> 6;
    int lane = tid & 63;
    if (wave < 2) {
        int b = wave;
        const int n = GB, m = PB;
        if (lane <= n) uarr[b][lane] = 0.0;
        if (lane <= m) parr[b][lane] = 0;
        int j = lane;
        bool valid = (j >= 1 && j <= m);
        double vj = 0.0;

        for (int i = 1; i <= n; ++i) {
            if (lane == 0) parr[b][0] = i;
            int j0 = 0;
            double minvj = 1e300;
            bool usedj = false;
            for (int guard = 0; guard < 4*PB; ++guard) {
                if (j == j0) usedj = true;
                int i0 = parr[b][j0];
                double u0 = uarr[b][i0];
                if (valid && !usedj) {
                    double cur = Ct[b][i0-1][j-1] - u0 - vj;
                    if (cur < minvj) { minvj = cur; wayarr[b][j] = j0; }
                }
                double bestv = (valid && !usedj) ? minvj : 1e300;
                int bestj = j;
                #pragma unroll
                for (int off = 32; off >= 1; off >>= 1) {
                    double ov = __shfl_xor(bestv, off);
                    int    oj = __shfl_xor(bestj, off);
                    if (ov < bestv || (ov == bestv && oj < bestj)) { bestv = ov; bestj = oj; }
                }
                double delta = bestv;
                if (j <= m) {
                    if (usedj) {
                        int pj = parr[b][j];
                        uarr[b][pj] += delta;
                        vj -= delta;
                    } else if (valid) {
                        minvj -= delta;
                    }
                }
                j0 = bestj;
                if (parr[b][j0] == 0) break;
            }
            int jj = j0;
            for (int guard = 0; guard < 2*PB && jj; ++guard) {
                int j1 = wayarr[b][jj];
                parr[b][jj] = parr[b][j1];
                jj = j1;
            }
        }

        // per-batch loss components
        double nvbd = (double)nvbs[b];
        double myb = 0.0, myd = 0.0, myf = 0.0, myu = 0.0;
        if (valid) {
            int pj = parr[b][j];
            int p = j - 1;
            if (pj > 0) {
                int ii = pj - 1;
                myb = ((double)fs[b][TOFF + p] - (double)fs[b][ii*ILS + p*2]) / nvbd;
                myd = 1.0 - (2.0*(double)fs[b][ii*ILS + p*2 + 1] + 1.0) /
                            ((double)fs[b][TOFF + 32 + p] + (double)fs[b][CNT_OFF + ii] + 1.0);
            } else {
                myf = (double)fs[b][TOFF + 64 + p];
                myu = 1.0;
            }
        }
        #pragma unroll
        for (int off = 32; off >= 1; off >>= 1) {
            myb += __shfl_xor(myb, off);
            myd += __shfl_xor(myd, off);
            myf += __shfl_xor(myf, off);
            myu += __shfl_xor(myu, off);
        }
        if (lane == 0) {
            double G = (double)GB;
            double bce  = 2.0 * myb / G;                                  // L_B = 2
            double dice = 1.0 * myd / G;                                  // L_D = 1
            double unm  = (myu > 0.0) ? 7.0 * 0.75 * myf / (myu * nvbd)   // L_U, alpha
                                      : 0.0;
            bres[b][0] = bce; bres[b][1] = dice; bres[b][2] = unm;
        }
    }
    __syncthreads();

    if (tid == 0) {
        double L[5] = {0,0,0,0,0};
        for (int b = 0; b < 2; ++b) {
            double bce = bres[b][0], dice = bres[b][1], unm = bres[b][2];
            double matched = bce + dice;
            double total = matched + unm;
            L[0] += total; L[1] += matched; L[2] += unm; L[3] += bce; L[4] += dice;
        }
        for (int k2 = 0; k2 < 5; ++k2) outp[k2] = (float)(L[k2] / 2.0);
    }
}

extern "C" void kernel_launch(void* const* d_in, const int* in_sizes, int n_in,
                              void* d_out, int out_size, void* d_ws, size_t ws_size,
                              hipStream_t stream)
{
    const float* logits = (const float*)d_in[0];
    const int* vb = (const int*)d_in[1];
    const int* gi = (const int*)d_in[2];
    int NV = in_sizes[1];

    float* ws = (float*)d_ws;
    size_t avail = ws_size / sizeof(float);
    int nblk = NBLK_DEF;
    while (nblk > 2 && (size_t)(64 + (size_t)(nblk + 8) * REGION) > avail) nblk -= 2;
    int half = nblk / 2;

    int*   b0ptr    = (int*)ws;                  // header (64 floats)
    float* partials = ws + 64;
    float* tmp      = partials + (size_t)nblk * REGION;

    hipLaunchKernelGGL(k_bound, dim3(1), dim3(256), 0, stream, vb, NV, b0ptr);
    hipLaunchKernelGGL(k_accum, dim3(nblk), dim3(256), 0, stream,
                       logits, gi, b0ptr, partials, NV, half);
    hipLaunchKernelGGL(k_reduce, dim3((REGION + 255)/256, 8), dim3(256), 0, stream,
                       partials, tmp, half);
    hipLaunchKernelGGL(k_final, dim3(1), dim3(256), 0, stream,
                       tmp, (float*)d_out);
}

// Round 5
// 181.670 us; speedup vs baseline: 3.2314x; 1.8361x over previous
//
#include <hip/hip_runtime.h>
#include <math.h>

#define PB 32
#define GB 24
#define NBUK 48
#define NH 256         // hist/scatter blocks
#define SL 16          // slices per bucket in accum
#define PART 160       // floats per accum-block partial: [5][32]

// ---------------- K_hist: per-block bucket histogram ----------------
__global__ __launch_bounds__(256) void k_hist(const int* __restrict__ gi, int NV,
                                              int* __restrict__ counts)
{
    __shared__ int h[NBUK];
    int t = threadIdx.x;
    if (t < NBUK) h[t] = 0;
    __syncthreads();
    int CH = (NV + NH - 1) / NH;
    int lo = blockIdx.x * CH, hi = lo + CH; if (hi > NV) hi = NV;
    for (int i = lo + t; i < hi; i += 256) atomicAdd(&h[gi[i]], 1);
    __syncthreads();
    if (t < NBUK) counts[t * NH + blockIdx.x] = h[t];
}

// ---------------- K_scan: exclusive scan (bucket-major) -> per-(bucket,block) offsets ----------------
__global__ __launch_bounds__(1024) void k_scan(const int* __restrict__ counts,
                                               int* __restrict__ offs, int* __restrict__ bs)
{
    __shared__ int tot[NBUK];
    __shared__ int bstart[NBUK + 1];
    int t = threadIdx.x, w = t >> 6, lane = t & 63;
    int c[3][4]; int excl[3];
    #pragma unroll
    for (int q = 0; q < 3; ++q) {
        int g = w * 3 + q;
        int base = g * NH + lane * 4;
        int s = 0;
        #pragma unroll
        for (int j = 0; j < 4; ++j) { c[q][j] = counts[base + j]; s += c[q][j]; }
        int inc = s;
        for (int off = 1; off < 64; off <<= 1) {
            int v = __shfl_up(inc, off);
            if (lane >= off) inc += v;
        }
        excl[q] = inc - s;
        int rt = __shfl(inc, 63);
        if (lane == 0) tot[g] = rt;
    }
    __syncthreads();
    if (t == 0) {
        int acc = 0;
        for (int g = 0; g < NBUK; ++g) { bstart[g] = acc; acc += tot[g]; }
        bstart[NBUK] = acc;
        for (int g = 0; g <= NBUK; ++g) bs[g] = bstart[g];
    }
    __syncthreads();
    #pragma unroll
    for (int q = 0; q < 3; ++q) {
        int g = w * 3 + q;
        int run = excl[q] + bstart[g];
        #pragma unroll
        for (int j = 0; j < 4; ++j) { offs[g * NH + lane * 4 + j] = run; run += c[q][j]; }
    }
}

// ---------------- K_scatter: stable rank + scatter voxel indices ----------------
__global__ __launch_bounds__(256) void k_scatter(const int* __restrict__ gi, int NV,
                                                 const int* __restrict__ offs,
                                                 int* __restrict__ sidx)
{
    __shared__ int cur[NBUK];
    __shared__ int wcnt[4][NBUK];
    int t = threadIdx.x, w = t >> 6, lane = t & 63;
    if (t < NBUK) cur[t] = offs[t * NH + blockIdx.x];
    int CH = (NV + NH - 1) / NH;
    int lo = blockIdx.x * CH, hi = lo + CH; if (hi > NV) hi = NV;
    unsigned long long below = (lane == 0) ? 0ull : ((~0ull) >> (64 - lane));

    for (int base = lo; base < hi; base += 256) {
        int v = base + t;
        bool act = (v < hi);
        int g = act ? gi[v] : -1;
        for (int j = t; j < 4 * NBUK; j += 256) (&wcnt[0][0])[j] = 0;
        __syncthreads();
        int rank_in_wave = 0;
        for (int q = 0; q < NBUK; ++q) {
            unsigned long long m = __ballot(g == q);
            if (m) {
                if (g == q) rank_in_wave = __popcll(m & below);
                if (lane == __ffsll((unsigned long long)m) - 1) wcnt[w][q] = __popcll(m);
            }
        }
        __syncthreads();
        if (act) {
            int pre = 0;
            for (int ww = 0; ww < w; ++ww) pre += wcnt[ww][g];
            sidx[cur[g] + pre + rank_in_wave] = v;
        }
        __syncthreads();
        if (t < NBUK) {
            int s = 0;
            for (int ww = 0; ww < 4; ++ww) s += wcnt[ww][t];
            cur[t] += s;
        }
        __syncthreads();
    }
}

// ---------------- K_accum2: uniform-il register accumulation (no atomics) ----------------
__global__ __launch_bounds__(256) void k_accum2(
    const float* __restrict__ logits, const int* __restrict__ sidx,
    const int* __restrict__ bs, float* __restrict__ partials)
{
    int g = blockIdx.x >> 4, s = blockIdx.x & 15;
    int b = (g >= GB) ? 1 : 0;
    int lo = bs[g], hi = bs[g + 1];
    int sz = hi - lo;
    int sl = (sz + SL - 1) / SL;
    int p0 = lo + s * sl, p1 = p0 + sl; if (p1 > hi) p1 = hi;

    int t = threadIdx.x, w = t >> 6, lane = t & 63;
    int vi = lane >> 3, c0 = (lane & 7) * 4;
    int wn = p1 - p0;
    int wl = (wn + 3) / 4;
    int q0 = p0 + w * wl, q1 = q0 + wl; if (q1 > p1) q1 = p1;

    const float* xb = logits + 32 * b + c0;
    float sx[4] = {0,0,0,0}, sg[4] = {0,0,0,0};
    float tn[4] = {0,0,0,0}, ts[4] = {0,0,0,0}, tf[4] = {0,0,0,0};

    #pragma unroll 2
    for (int pos = q0; pos < q1; pos += 8) {
        int pv = pos + vi;
        if (pv < q1) {
            int idx = sidx[pv];
            float4 xq = *(const float4*)(xb + (size_t)idx * 64);
            float xs[4] = {xq.x, xq.y, xq.z, xq.w};
            #pragma unroll
            for (int e = 0; e < 4; ++e) {
                float x  = xs[e];
                float ax = fabsf(x);
                float ex = __expf(-ax);
                float neg = fmaxf(x, 0.f) + __logf(1.f + ex);    // softplus(x)
                float r  = __builtin_amdgcn_rcpf(1.f + ex);
                float sig = (x >= 0.f) ? r : ex * r;             // sigmoid(x)
                sx[e] += x;
                sg[e] += sig;
                tn[e] += neg;
                ts[e] += sig;
                tf[e] += neg * sig * sig;
            }
        }
    }

    // reduce across the 8 voxel-groups (lanes with same lane&7)
    #pragma unroll
    for (int off = 8; off <= 32; off <<= 1) {
        #pragma unroll
        for (int e = 0; e < 4; ++e) {
            sx[e] += __shfl_xor(sx[e], off);
            sg[e] += __shfl_xor(sg[e], off);
            tn[e] += __shfl_xor(tn[e], off);
            ts[e] += __shfl_xor(ts[e], off);
            tf[e] += __shfl_xor(tf[e], off);
        }
    }

    __shared__ float red[4][5][PB];
    if (lane < 8) {
        #pragma unroll
        for (int e = 0; e < 4; ++e) {
            red[w][0][c0 + e] = sx[e];
            red[w][1][c0 + e] = sg[e];
            red[w][2][c0 + e] = tn[e];
            red[w][3][c0 + e] = ts[e];
            red[w][4][c0 + e] = tf[e];
        }
    }
    __syncthreads();
    float* op = partials + (size_t)blockIdx.x * PART;
    for (int j = t; j < PART; j += 256)
        op[j] = (&red[0][0][0])[j] + (&red[1][0][0])[j] + (&red[2][0][0])[j] + (&red[3][0][0])[j];
}

// ---------------- K_reduce2: sum the 16 slices per bucket ----------------
__global__ __launch_bounds__(256) void k_reduce2(const float* __restrict__ partials,
                                                 float* __restrict__ fin)
{
    int j = blockIdx.x * 256 + threadIdx.x;
    if (j >= NBUK * PART) return;
    int g = j / PART, r = j % PART;
    const float* base = partials + (size_t)g * SL * PART + r;
    float s = 0.f;
    #pragma unroll
    for (int k = 0; k < SL; ++k) s += base[(size_t)k * PART];
    fin[j] = s;
}

// ---------------- K_final: cost build + JV Hungarian + losses ----------------
__global__ __launch_bounds__(256) void k_final(
    const float* __restrict__ fin, const int* __restrict__ bs, float* __restrict__ outp)
{
    __shared__ float fs2[NBUK][5][PB];   // per (bucket): sx, ssig, tneg_p, tsig_p, tfoc_p
    __shared__ float tneg[2][PB], tsig[2][PB], tfoc[2][PB];
    __shared__ float cntf[NBUK];
    __shared__ float nvbs[2];
    __shared__ double Ct[2][GB][PB];
    __shared__ double uarr[2][GB+1];
    __shared__ int    parr[2][PB+1];
    __shared__ int    wayarr[2][PB+1];
    __shared__ double bres[2][3];

    int tid = threadIdx.x;
    for (int j = tid; j < NBUK * 5 * PB; j += 256) (&fs2[0][0][0])[j] = fin[j];
    if (tid < NBUK) cntf[tid] = (float)(bs[tid + 1] - bs[tid]);
    __syncthreads();

    if (tid < 64) {
        int b = tid >> 5, p = tid & 31;
        float a = 0.f, c = 0.f, d = 0.f;
        for (int i = 0; i < GB; ++i) {
            a += fs2[b*GB + i][2][p];
            c += fs2[b*GB + i][3][p];
            d += fs2[b*GB + i][4][p];
        }
        tneg[b][p] = a; tsig[b][p] = c; tfoc[b][p] = d;
    }
    if (tid >= 64 && tid < 66) {
        int b = tid - 64; float s = 0.f;
        for (int i = 0; i < GB; ++i) s += cntf[b*GB + i];
        nvbs[b] = s;
    }
    __syncthreads();

    // cost matrix (L_B=2, L_D=1), float math as reference then double for JV
    for (int idx = tid; idx < 2*GB*PB; idx += 256) {
        int b = idx / (GB*PB), r = idx % (GB*PB), i = r / PB, j = r % PB;
        float nv = nvbs[b];
        float sx   = fs2[b*GB + i][0][j];
        float ssig = fs2[b*GB + i][1][j];
        float bceC  = 2.0f * (tneg[b][j] - sx) / nv;
        float diceC = 1.0f - (2.f*ssig + 1.f) / (tsig[b][j] + cntf[b*GB + i] + 1.f);
        Ct[b][i][j] = (double)(bceC + diceC);
    }
    __syncthreads();

    // JV Hungarian: wave b handles batch b; lane = column j
    int wave = tid >> 6;
    int lane = tid & 63;
    if (wave < 2) {
        int b = wave;
        const int n = GB, m = PB;
        if (lane <= n) uarr[b][lane] = 0.0;
        if (lane <= m) parr[b][lane] = 0;
        int j = lane;
        bool valid = (j >= 1 && j <= m);
        double vj = 0.0;

        for (int i = 1; i <= n; ++i) {
            if (lane == 0) parr[b][0] = i;
            int j0 = 0;
            double minvj = 1e300;
            bool usedj = false;
            for (int guard = 0; guard < 4*PB; ++guard) {
                if (j == j0) usedj = true;
                int i0 = parr[b][j0];
                double u0 = uarr[b][i0];
                if (valid && !usedj) {
                    double cur = Ct[b][i0-1][j-1] - u0 - vj;
                    if (cur < minvj) { minvj = cur; wayarr[b][j] = j0; }
                }
                double bestv = (valid && !usedj) ? minvj : 1e300;
                int bestj = j;
                #pragma unroll
                for (int off = 32; off >= 1; off >>= 1) {
                    double ov = __shfl_xor(bestv, off);
                    int    oj = __shfl_xor(bestj, off);
                    if (ov < bestv || (ov == bestv && oj < bestj)) { bestv = ov; bestj = oj; }
                }
                double delta = bestv;
                if (j <= m) {
                    if (usedj) {
                        int pj = parr[b][j];
                        uarr[b][pj] += delta;
                        vj -= delta;
                    } else if (valid) {
                        minvj -= delta;
                    }
                }
                j0 = bestj;
                if (parr[b][j0] == 0) break;
            }
            int jj = j0;
            for (int guard = 0; guard < 2*PB && jj; ++guard) {
                int j1 = wayarr[b][jj];
                parr[b][jj] = parr[b][j1];
                jj = j1;
            }
        }

        // per-batch loss components
        double nvbd = (double)nvbs[b];
        double myb = 0.0, myd = 0.0, myf = 0.0, myu = 0.0;
        if (valid) {
            int pj = parr[b][j];
            int p = j - 1;
            if (pj > 0) {
                int ii = pj - 1;
                myb = ((double)tneg[b][p] - (double)fs2[b*GB + ii][0][p]) / nvbd;
                myd = 1.0 - (2.0*(double)fs2[b*GB + ii][1][p] + 1.0) /
                            ((double)tsig[b][p] + (double)cntf[b*GB + ii] + 1.0);
            } else {
                myf = (double)tfoc[b][p];
                myu = 1.0;
            }
        }
        #pragma unroll
        for (int off = 32; off >= 1; off >>= 1) {
            myb += __shfl_xor(myb, off);
            myd += __shfl_xor(myd, off);
            myf += __shfl_xor(myf, off);
            myu += __shfl_xor(myu, off);
        }
        if (lane == 0) {
            double G = (double)GB;
            double bce  = 2.0 * myb / G;                                  // L_B = 2
            double dice = 1.0 * myd / G;                                  // L_D = 1
            double unm  = (myu > 0.0) ? 7.0 * 0.75 * myf / (myu * nvbd)   // L_U, alpha
                                      : 0.0;
            bres[b][0] = bce; bres[b][1] = dice; bres[b][2] = unm;
        }
    }
    __syncthreads();

    if (tid == 0) {
        double L[5] = {0,0,0,0,0};
        for (int b = 0; b < 2; ++b) {
            double bce = bres[b][0], dice = bres[b][1], unm = bres[b][2];
            double matched = bce + dice;
            double total = matched + unm;
            L[0] += total; L[1] += matched; L[2] += unm; L[3] += bce; L[4] += dice;
        }
        for (int k2 = 0; k2 < 5; ++k2) outp[k2] = (float)(L[k2] / 2.0);
    }
}

extern "C" void kernel_launch(void* const* d_in, const int* in_sizes, int n_in,
                              void* d_out, int out_size, void* d_ws, size_t ws_size,
                              hipStream_t stream)
{
    const float* logits = (const float*)d_in[0];
    const int* gi = (const int*)d_in[2];
    int NV = in_sizes[1];

    int* wsi = (int*)d_ws;
    int* counts = wsi;                       // 48*256
    int* offs   = counts + NBUK * NH;        // 48*256
    int* bs     = offs + NBUK * NH;          // 64
    int* sidx   = bs + 64;                   // NV
    float* partials = (float*)(sidx + NV);   // 768*160
    float* fin      = partials + NBUK * SL * PART;  // 7680

    hipLaunchKernelGGL(k_hist,    dim3(NH), dim3(256), 0, stream, gi, NV, counts);
    hipLaunchKernelGGL(k_scan,    dim3(1), dim3(1024), 0, stream, counts, offs, bs);
    hipLaunchKernelGGL(k_scatter, dim3(NH), dim3(256), 0, stream, gi, NV, offs, sidx);
    hipLaunchKernelGGL(k_accum2,  dim3(NBUK * SL), dim3(256), 0, stream, logits, sidx, bs, partials);
    hipLaunchKernelGGL(k_reduce2, dim3((NBUK * PART + 255) / 256), dim3(256), 0, stream, partials, fin);
    hipLaunchKernelGGL(k_final,   dim3(1), dim3(256), 0, stream, fin, bs, (float*)d_out);
}

// Round 6
// 136.728 us; speedup vs baseline: 4.2936x; 1.3287x over previous
//
#include <hip/hip_runtime.h>
#include <math.h>

#define PB 32
#define GB 24
#define NBUK 48
#define NH 256         // hist/scatter blocks
#define SL 16          // slices per bucket in accum
#define PART 160       // floats per accum-block partial: [5][32]

// ---------------- K_hist: per-block bucket histogram ----------------
__global__ __launch_bounds__(256) void k_hist(const int* __restrict__ gi, int NV,
                                              int* __restrict__ counts)
{
    __shared__ int h[NBUK];
    int t = threadIdx.x;
    if (t < NBUK) h[t] = 0;
    __syncthreads();
    int CH = (NV + NH - 1) / NH;
    int lo = blockIdx.x * CH, hi = lo + CH; if (hi > NV) hi = NV;
    for (int i = lo + t; i < hi; i += 256) atomicAdd(&h[gi[i]], 1);
    __syncthreads();
    if (t < NBUK) counts[t * NH + blockIdx.x] = h[t];
}

// ---------------- K_scan: exclusive scan (bucket-major) -> per-(bucket,block) offsets ----------------
__global__ __launch_bounds__(1024) void k_scan(const int* __restrict__ counts,
                                               int* __restrict__ offs, int* __restrict__ bs)
{
    __shared__ int tot[NBUK];
    __shared__ int bstart[NBUK + 1];
    int t = threadIdx.x, w = t >> 6, lane = t & 63;
    int c[3][4]; int excl[3];
    #pragma unroll
    for (int q = 0; q < 3; ++q) {
        int g = w * 3 + q;
        int base = g * NH + lane * 4;
        int s = 0;
        #pragma unroll
        for (int j = 0; j < 4; ++j) { c[q][j] = counts[base + j]; s += c[q][j]; }
        int inc = s;
        for (int off = 1; off < 64; off <<= 1) {
            int v = __shfl_up(inc, off);
            if (lane >= off) inc += v;
        }
        excl[q] = inc - s;
        int rt = __shfl(inc, 63);
        if (lane == 0) tot[g] = rt;
    }
    __syncthreads();
    if (t == 0) {
        int acc = 0;
        for (int g = 0; g < NBUK; ++g) { bstart[g] = acc; acc += tot[g]; }
        bstart[NBUK] = acc;
        for (int g = 0; g <= NBUK; ++g) bs[g] = bstart[g];
    }
    __syncthreads();
    #pragma unroll
    for (int q = 0; q < 3; ++q) {
        int g = w * 3 + q;
        int run = excl[q] + bstart[g];
        #pragma unroll
        for (int j = 0; j < 4; ++j) { offs[g * NH + lane * 4 + j] = run; run += c[q][j]; }
    }
}

// ---------------- K_scatter: stable rank + scatter voxel indices ----------------
__global__ __launch_bounds__(256) void k_scatter(const int* __restrict__ gi, int NV,
                                                 const int* __restrict__ offs,
                                                 int* __restrict__ sidx)
{
    __shared__ int cur[NBUK];
    __shared__ int wcnt[4][NBUK];
    int t = threadIdx.x, w = t >> 6, lane = t & 63;
    if (t < NBUK) cur[t] = offs[t * NH + blockIdx.x];
    int CH = (NV + NH - 1) / NH;
    int lo = blockIdx.x * CH, hi = lo + CH; if (hi > NV) hi = NV;
    unsigned long long below = (lane == 0) ? 0ull : ((~0ull) >> (64 - lane));

    for (int base = lo; base < hi; base += 256) {
        int v = base + t;
        bool act = (v < hi);
        int g = act ? gi[v] : -1;
        for (int j = t; j < 4 * NBUK; j += 256) (&wcnt[0][0])[j] = 0;
        __syncthreads();
        int rank_in_wave = 0;
        for (int q = 0; q < NBUK; ++q) {
            unsigned long long m = __ballot(g == q);
            if (m) {
                if (g == q) rank_in_wave = __popcll(m & below);
                if (lane == __ffsll((unsigned long long)m) - 1) wcnt[w][q] = __popcll(m);
            }
        }
        __syncthreads();
        if (act) {
            int pre = 0;
            for (int ww = 0; ww < w; ++ww) pre += wcnt[ww][g];
            sidx[cur[g] + pre + rank_in_wave] = v;
        }
        __syncthreads();
        if (t < NBUK) {
            int s = 0;
            for (int ww = 0; ww < 4; ++ww) s += wcnt[ww][t];
            cur[t] += s;
        }
        __syncthreads();
    }
}

// ---------------- K_accum2: uniform-il register accumulation (no atomics) ----------------
__global__ __launch_bounds__(256) void k_accum2(
    const float* __restrict__ logits, const int* __restrict__ sidx,
    const int* __restrict__ bs, float* __restrict__ partials)
{
    int g = blockIdx.x >> 4, s = blockIdx.x & 15;
    int b = (g >= GB) ? 1 : 0;
    int lo = bs[g], hi = bs[g + 1];
    int sz = hi - lo;
    int sl = (sz + SL - 1) / SL;
    int p0 = lo + s * sl, p1 = p0 + sl; if (p1 > hi) p1 = hi;

    int t = threadIdx.x, w = t >> 6, lane = t & 63;
    int vi = lane >> 3, c0 = (lane & 7) * 4;
    int wn = p1 - p0;
    int wl = (wn + 3) / 4;
    int q0 = p0 + w * wl, q1 = q0 + wl; if (q1 > p1) q1 = p1;

    const float* xb = logits + 32 * b + c0;
    float sx[4] = {0,0,0,0}, sg[4] = {0,0,0,0};
    float tn[4] = {0,0,0,0}, ts[4] = {0,0,0,0}, tf[4] = {0,0,0,0};

    #pragma unroll 2
    for (int pos = q0; pos < q1; pos += 8) {
        int pv = pos + vi;
        if (pv < q1) {
            int idx = sidx[pv];
            float4 xq = *(const float4*)(xb + (size_t)idx * 64);
            float xs[4] = {xq.x, xq.y, xq.z, xq.w};
            #pragma unroll
            for (int e = 0; e < 4; ++e) {
                float x  = xs[e];
                float ax = fabsf(x);
                float ex = __expf(-ax);
                float neg = fmaxf(x, 0.f) + __logf(1.f + ex);    // softplus(x)
                float r  = __builtin_amdgcn_rcpf(1.f + ex);
                float sig = (x >= 0.f) ? r : ex * r;             // sigmoid(x)
                sx[e] += x;
                sg[e] += sig;
                tn[e] += neg;
                ts[e] += sig;
                tf[e] += neg * sig * sig;
            }
        }
    }

    // reduce across the 8 voxel-groups (lanes with same lane&7)
    #pragma unroll
    for (int off = 8; off <= 32; off <<= 1) {
        #pragma unroll
        for (int e = 0; e < 4; ++e) {
            sx[e] += __shfl_xor(sx[e], off);
            sg[e] += __shfl_xor(sg[e], off);
            tn[e] += __shfl_xor(tn[e], off);
            ts[e] += __shfl_xor(ts[e], off);
            tf[e] += __shfl_xor(tf[e], off);
        }
    }

    __shared__ float red[4][5][PB];
    if (lane < 8) {
        #pragma unroll
        for (int e = 0; e < 4; ++e) {
            red[w][0][c0 + e] = sx[e];
            red[w][1][c0 + e] = sg[e];
            red[w][2][c0 + e] = tn[e];
            red[w][3][c0 + e] = ts[e];
            red[w][4][c0 + e] = tf[e];
        }
    }
    __syncthreads();
    float* op = partials + (size_t)blockIdx.x * PART;
    for (int j = t; j < PART; j += 256)
        op[j] = (&red[0][0][0])[j] + (&red[1][0][0])[j] + (&red[2][0][0])[j] + (&red[3][0][0])[j];
}

// ---------------- K_final: fused slice-reduce + cost build + f32 JV Hungarian + losses ----------------
__global__ __launch_bounds__(256) void k_final(
    const float* __restrict__ partials, const int* __restrict__ bs, float* __restrict__ outp)
{
    __shared__ float fs2[NBUK][5][PB];   // per (bucket): sx, ssig, tneg_p, tsig_p, tfoc_p
    __shared__ float tneg[2][PB], tsig[2][PB], tfoc[2][PB];
    __shared__ float cntf[NBUK];
    __shared__ float nvbs[2];
    __shared__ float Ct[2][GB][PB];
    __shared__ float uarr[2][GB+1];
    __shared__ int   parr[2][PB+1];
    __shared__ int   wayarr[2][PB+1];
    __shared__ double bres[2][3];

    int tid = threadIdx.x;
    // fused k_reduce2: sum 16 slices per bucket
    for (int j = tid; j < NBUK * PART; j += 256) {
        int g = j / PART, r = j % PART;
        const float* base = partials + (size_t)g * SL * PART + r;
        float s = 0.f;
        #pragma unroll
        for (int k = 0; k < SL; ++k) s += base[(size_t)k * PART];
        (&fs2[0][0][0])[j] = s;
    }
    if (tid < NBUK) cntf[tid] = (float)(bs[tid + 1] - bs[tid]);
    __syncthreads();

    if (tid < 64) {
        int b = tid >> 5, p = tid & 31;
        float a = 0.f, c = 0.f, d = 0.f;
        for (int i = 0; i < GB; ++i) {
            a += fs2[b*GB + i][2][p];
            c += fs2[b*GB + i][3][p];
            d += fs2[b*GB + i][4][p];
        }
        tneg[b][p] = a; tsig[b][p] = c; tfoc[b][p] = d;
    }
    if (tid >= 64 && tid < 66) {
        int b = tid - 64; float s = 0.f;
        for (int i = 0; i < GB; ++i) s += cntf[b*GB + i];
        nvbs[b] = s;
    }
    __syncthreads();

    // cost matrix (L_B=2, L_D=1), float math as reference
    for (int idx = tid; idx < 2*GB*PB; idx += 256) {
        int b = idx / (GB*PB), r = idx % (GB*PB), i = r / PB, j = r % PB;
        float nv = nvbs[b];
        float sx   = fs2[b*GB + i][0][j];
        float ssig = fs2[b*GB + i][1][j];
        float bceC  = 2.0f * (tneg[b][j] - sx) / nv;
        float diceC = 1.0f - (2.f*ssig + 1.f) / (tsig[b][j] + cntf[b*GB + i] + 1.f);
        Ct[b][i][j] = bceC + diceC;
    }
    __syncthreads();

    // f32 JV Hungarian: wave b handles batch b; lane = column j; ballot-argmin
    int wave = tid >> 6;
    int lane = tid & 63;
    if (wave < 2) {
        int b = wave;
        const int n = GB, m = PB;
        if (lane <= n) uarr[b][lane] = 0.f;
        if (lane <= m) parr[b][lane] = 0;
        int j = lane;
        bool valid = (j >= 1 && j <= m);
        float vj = 0.f;

        for (int i = 1; i <= n; ++i) {
            if (lane == 0) parr[b][0] = i;
            int j0 = 0;
            float minvj = 3e38f;
            bool usedj = false;
            for (int guard = 0; guard < 4*PB; ++guard) {
                if (j == j0) usedj = true;
                int i0 = parr[b][j0];
                float u0 = uarr[b][i0];
                if (valid && !usedj) {
                    float cur = Ct[b][i0-1][j-1] - u0 - vj;
                    if (cur < minvj) { minvj = cur; wayarr[b][j] = j0; }
                }
                float cand = (valid && !usedj) ? minvj : 3e38f;
                float dm = cand;
                #pragma unroll
                for (int off = 32; off >= 1; off >>= 1)
                    dm = fminf(dm, __shfl_xor(dm, off));
                unsigned long long msk = __ballot(cand == dm);
                int bestj = (int)__ffsll(msk) - 1;
                float delta = dm;
                if (j <= m) {
                    if (usedj) {
                        int pj = parr[b][j];        // distinct rows per used column
                        uarr[b][pj] += delta;
                        vj -= delta;
                    } else if (valid) {
                        minvj -= delta;
                    }
                }
                j0 = bestj;
                if (parr[b][j0] == 0) break;
            }
            int jj = j0;
            for (int guard = 0; guard < 2*PB && jj; ++guard) {
                int j1 = wayarr[b][jj];
                parr[b][jj] = parr[b][j1];
                jj = j1;
            }
        }

        // per-batch loss components (double for exact final sums)
        double nvbd = (double)nvbs[b];
        double myb = 0.0, myd = 0.0, myf = 0.0, myu = 0.0;
        if (valid) {
            int pj = parr[b][j];
            int p = j - 1;
            if (pj > 0) {
                int ii = pj - 1;
                myb = ((double)tneg[b][p] - (double)fs2[b*GB + ii][0][p]) / nvbd;
                myd = 1.0 - (2.0*(double)fs2[b*GB + ii][1][p] + 1.0) /
                            ((double)tsig[b][p] + (double)cntf[b*GB + ii] + 1.0);
            } else {
                myf = (double)tfoc[b][p];
                myu = 1.0;
            }
        }
        #pragma unroll
        for (int off = 32; off >= 1; off >>= 1) {
            myb += __shfl_xor(myb, off);
            myd += __shfl_xor(myd, off);
            myf += __shfl_xor(myf, off);
            myu += __shfl_xor(myu, off);
        }
        if (lane == 0) {
            double G = (double)GB;
            double bce  = 2.0 * myb / G;                                  // L_B = 2
            double dice = 1.0 * myd / G;                                  // L_D = 1
            double unm  = (myu > 0.0) ? 7.0 * 0.75 * myf / (myu * nvbd)   // L_U, alpha
                                      : 0.0;
            bres[b][0] = bce; bres[b][1] = dice; bres[b][2] = unm;
        }
    }
    __syncthreads();

    if (tid == 0) {
        double L[5] = {0,0,0,0,0};
        for (int b = 0; b < 2; ++b) {
            double bce = bres[b][0], dice = bres[b][1], unm = bres[b][2];
            double matched = bce + dice;
            double total = matched + unm;
            L[0] += total; L[1] += matched; L[2] += unm; L[3] += bce; L[4] += dice;
        }
        for (int k2 = 0; k2 < 5; ++k2) outp[k2] = (float)(L[k2] / 2.0);
    }
}

extern "C" void kernel_launch(void* const* d_in, const int* in_sizes, int n_in,
                              void* d_out, int out_size, void* d_ws, size_t ws_size,
                              hipStream_t stream)
{
    const float* logits = (const float*)d_in[0];
    const int* gi = (const int*)d_in[2];
    int NV = in_sizes[1];

    int* wsi = (int*)d_ws;
    int* counts = wsi;                       // 48*256
    int* offs   = counts + NBUK * NH;        // 48*256
    int* bs     = offs + NBUK * NH;          // 64
    int* sidx   = bs + 64;                   // NV
    float* partials = (float*)(sidx + NV);   // 768*160

    hipLaunchKernelGGL(k_hist,    dim3(NH), dim3(256), 0, stream, gi, NV, counts);
    hipLaunchKernelGGL(k_scan,    dim3(1), dim3(1024), 0, stream, counts, offs, bs);
    hipLaunchKernelGGL(k_scatter, dim3(NH), dim3(256), 0, stream, gi, NV, offs, sidx);
    hipLaunchKernelGGL(k_accum2,  dim3(NBUK * SL), dim3(256), 0, stream, logits, sidx, bs, partials);
    hipLaunchKernelGGL(k_final,   dim3(1), dim3(256), 0, stream, partials, bs, (float*)d_out);
}

// Round 7
// 100.564 us; speedup vs baseline: 5.8376x; 1.3596x over previous
//
#include <hip/hip_runtime.h>
#include <math.h>

#define PB 32
#define GB 24
#define NBUK 48
#define NH 256         // hist/scatter blocks
#define SL 16          // slices per bucket in accum
#define PART 160       // floats per accum-block partial: [5][32]

// ---------------- K_hist: per-block bucket histogram ----------------
__global__ __launch_bounds__(256) void k_hist(const int* __restrict__ gi, int NV,
                                              int* __restrict__ counts)
{
    __shared__ int h[NBUK];
    int t = threadIdx.x;
    if (t < NBUK) h[t] = 0;
    __syncthreads();
    int CH = (NV + NH - 1) / NH;
    int lo = blockIdx.x * CH, hi = lo + CH; if (hi > NV) hi = NV;
    for (int i = lo + t; i < hi; i += 256) atomicAdd(&h[gi[i]], 1);
    __syncthreads();
    if (t < NBUK) counts[t * NH + blockIdx.x] = h[t];
}

// ---------------- K_scan: exclusive scan (bucket-major) -> per-(bucket,block) offsets ----------------
__global__ __launch_bounds__(1024) void k_scan(const int* __restrict__ counts,
                                               int* __restrict__ offs, int* __restrict__ bs)
{
    __shared__ int tot[NBUK];
    __shared__ int bstart[NBUK + 1];
    int t = threadIdx.x, w = t >> 6, lane = t & 63;
    int c[3][4]; int excl[3];
    #pragma unroll
    for (int q = 0; q < 3; ++q) {
        int g = w * 3 + q;
        int base = g * NH + lane * 4;
        int s = 0;
        #pragma unroll
        for (int j = 0; j < 4; ++j) { c[q][j] = counts[base + j]; s += c[q][j]; }
        int inc = s;
        for (int off = 1; off < 64; off <<= 1) {
            int v = __shfl_up(inc, off);
            if (lane >= off) inc += v;
        }
        excl[q] = inc - s;
        int rt = __shfl(inc, 63);
        if (lane == 0) tot[g] = rt;
    }
    __syncthreads();
    if (t == 0) {
        int acc = 0;
        for (int g = 0; g < NBUK; ++g) { bstart[g] = acc; acc += tot[g]; }
        bstart[NBUK] = acc;
        for (int g = 0; g <= NBUK; ++g) bs[g] = bstart[g];
    }
    __syncthreads();
    #pragma unroll
    for (int q = 0; q < 3; ++q) {
        int g = w * 3 + q;
        int run = excl[q] + bstart[g];
        #pragma unroll
        for (int j = 0; j < 4; ++j) { offs[g * NH + lane * 4 + j] = run; run += c[q][j]; }
    }
}

// ---------------- K_scatter: stable rank + scatter voxel indices ----------------
__global__ __launch_bounds__(256) void k_scatter(const int* __restrict__ gi, int NV,
                                                 const int* __restrict__ offs,
                                                 int* __restrict__ sidx)
{
    __shared__ int cur[NBUK];
    __shared__ int wcnt[4][NBUK];
    int t = threadIdx.x, w = t >> 6, lane = t & 63;
    if (t < NBUK) cur[t] = offs[t * NH + blockIdx.x];
    int CH = (NV + NH - 1) / NH;
    int lo = blockIdx.x * CH, hi = lo + CH; if (hi > NV) hi = NV;
    unsigned long long below = (lane == 0) ? 0ull : ((~0ull) >> (64 - lane));

    for (int base = lo; base < hi; base += 256) {
        int v = base + t;
        bool act = (v < hi);
        int g = act ? gi[v] : -1;
        for (int j = t; j < 4 * NBUK; j += 256) (&wcnt[0][0])[j] = 0;
        __syncthreads();
        int rank_in_wave = 0;
        for (int q = 0; q < NBUK; ++q) {
            unsigned long long m = __ballot(g == q);
            if (m) {
                if (g == q) rank_in_wave = __popcll(m & below);
                if (lane == __ffsll((unsigned long long)m) - 1) wcnt[w][q] = __popcll(m);
            }
        }
        __syncthreads();
        if (act) {
            int pre = 0;
            for (int ww = 0; ww < w; ++ww) pre += wcnt[ww][g];
            sidx[cur[g] + pre + rank_in_wave] = v;
        }
        __syncthreads();
        if (t < NBUK) {
            int s = 0;
            for (int ww = 0; ww < 4; ++ww) s += wcnt[ww][t];
            cur[t] += s;
        }
        __syncthreads();
    }
}

// ---------------- K_accum2: uniform-il register accumulation (no atomics) ----------------
__global__ __launch_bounds__(256) void k_accum2(
    const float* __restrict__ logits, const int* __restrict__ sidx,
    const int* __restrict__ bs, float* __restrict__ partials)
{
    int g = blockIdx.x >> 4, s = blockIdx.x & 15;
    int b = (g >= GB) ? 1 : 0;
    int lo = bs[g], hi = bs[g + 1];
    int sz = hi - lo;
    int sl = (sz + SL - 1) / SL;
    int p0 = lo + s * sl, p1 = p0 + sl; if (p1 > hi) p1 = hi;

    int t = threadIdx.x, w = t >> 6, lane = t & 63;
    int vi = lane >> 3, c0 = (lane & 7) * 4;
    int wn = p1 - p0;
    int wl = (wn + 3) / 4;
    int q0 = p0 + w * wl, q1 = q0 + wl; if (q1 > p1) q1 = p1;

    const float* xb = logits + 32 * b + c0;
    float sx[4] = {0,0,0,0}, sg[4] = {0,0,0,0};
    float tn[4] = {0,0,0,0}, ts[4] = {0,0,0,0}, tf[4] = {0,0,0,0};

    #pragma unroll 2
    for (int pos = q0; pos < q1; pos += 8) {
        int pv = pos + vi;
        if (pv < q1) {
            int idx = sidx[pv];
            float4 xq = *(const float4*)(xb + (size_t)idx * 64);
            float xs[4] = {xq.x, xq.y, xq.z, xq.w};
            #pragma unroll
            for (int e = 0; e < 4; ++e) {
                float x  = xs[e];
                float ax = fabsf(x);
                float ex = __expf(-ax);
                float neg = fmaxf(x, 0.f) + __logf(1.f + ex);    // softplus(x)
                float r  = __builtin_amdgcn_rcpf(1.f + ex);
                float sig = (x >= 0.f) ? r : ex * r;             // sigmoid(x)
                sx[e] += x;
                sg[e] += sig;
                tn[e] += neg;
                ts[e] += sig;
                tf[e] += neg * sig * sig;
            }
        }
    }

    // reduce across the 8 voxel-groups (lanes with same lane&7)
    #pragma unroll
    for (int off = 8; off <= 32; off <<= 1) {
        #pragma unroll
        for (int e = 0; e < 4; ++e) {
            sx[e] += __shfl_xor(sx[e], off);
            sg[e] += __shfl_xor(sg[e], off);
            tn[e] += __shfl_xor(tn[e], off);
            ts[e] += __shfl_xor(ts[e], off);
            tf[e] += __shfl_xor(tf[e], off);
        }
    }

    __shared__ float red[4][5][PB];
    if (lane < 8) {
        #pragma unroll
        for (int e = 0; e < 4; ++e) {
            red[w][0][c0 + e] = sx[e];
            red[w][1][c0 + e] = sg[e];
            red[w][2][c0 + e] = tn[e];
            red[w][3][c0 + e] = ts[e];
            red[w][4][c0 + e] = tf[e];
        }
    }
    __syncthreads();
    float* op = partials + (size_t)blockIdx.x * PART;
    for (int j = t; j < PART; j += 256)
        op[j] = (&red[0][0][0])[j] + (&red[1][0][0])[j] + (&red[2][0][0])[j] + (&red[3][0][0])[j];
}

// DPP min over 64 lanes -> uniform scalar (4 row_shr mins + 4 readlanes)
#define DPPMIN(ctrl) { int tdp = __builtin_amdgcn_update_dpp(vbits, vbits, ctrl, 0xf, 0xf, false); \
    vbits = __float_as_int(fminf(__int_as_float(vbits), __int_as_float(tdp))); }
__device__ __forceinline__ float wave_min64(float x) {
    int vbits = __float_as_int(x);
    DPPMIN(0x111); DPPMIN(0x112); DPPMIN(0x114); DPPMIN(0x118);
    float a = __int_as_float(__builtin_amdgcn_readlane(vbits, 15));
    float b = __int_as_float(__builtin_amdgcn_readlane(vbits, 31));
    float c = __int_as_float(__builtin_amdgcn_readlane(vbits, 47));
    float d = __int_as_float(__builtin_amdgcn_readlane(vbits, 63));
    return fminf(fminf(a, b), fminf(c, d));
}

// ---------------- K_final: fused slice-reduce + cost build + register JV Hungarian + losses ----------------
__global__ __launch_bounds__(1024) void k_final(
    const float* __restrict__ partials, const int* __restrict__ bs, float* __restrict__ outp)
{
    __shared__ float fs2[NBUK][5][PB];   // per (bucket): sx, ssig, tneg_p, tsig_p, tfoc_p
    __shared__ float tneg[2][PB], tsig[2][PB], tfoc[2][PB];
    __shared__ float cntf[NBUK];
    __shared__ float nvbs[2];
    __shared__ float Ct[2][GB][PB];
    __shared__ float uincr[2][GB];
    __shared__ double bres[2][3];

    int tid = threadIdx.x;
    // fused slice-reduce: sum 16 slices per bucket (1024 threads)
    for (int j = tid; j < NBUK * PART; j += 1024) {
        int g = j / PART, r = j % PART;
        const float* base = partials + (size_t)g * SL * PART + r;
        float s = 0.f;
        #pragma unroll
        for (int k = 0; k < SL; ++k) s += base[(size_t)k * PART];
        (&fs2[0][0][0])[j] = s;
    }
    if (tid < NBUK) cntf[tid] = (float)(bs[tid + 1] - bs[tid]);
    __syncthreads();

    if (tid < 64) {
        int b = tid >> 5, p = tid & 31;
        float a = 0.f, c = 0.f, d = 0.f;
        for (int i = 0; i < GB; ++i) {
            a += fs2[b*GB + i][2][p];
            c += fs2[b*GB + i][3][p];
            d += fs2[b*GB + i][4][p];
        }
        tneg[b][p] = a; tsig[b][p] = c; tfoc[b][p] = d;
    }
    if (tid >= 64 && tid < 66) {
        int b = tid - 64; float s = 0.f;
        for (int i = 0; i < GB; ++i) s += cntf[b*GB + i];
        nvbs[b] = s;
    }
    __syncthreads();

    // cost matrix (L_B=2, L_D=1), float math as reference
    for (int idx = tid; idx < 2*GB*PB; idx += 1024) {
        int b = idx / (GB*PB), r = idx % (GB*PB), i = r / PB, j = r % PB;
        float nv = nvbs[b];
        float sx   = fs2[b*GB + i][0][j];
        float ssig = fs2[b*GB + i][1][j];
        float bceC  = 2.0f * (tneg[b][j] - sx) / nv;
        float diceC = 1.0f - (2.f*ssig + 1.f) / (tsig[b][j] + cntf[b*GB + i] + 1.f);
        Ct[b][i][j] = bceC + diceC;
    }
    __syncthreads();

    // Register JV Hungarian (absolute-distance form): wave b = batch b, lane = column j.
    // State per lane: p[j], way[j], v[j], M[j], Duse[j]; u distributed lane r -> u[r+1].
    // Exact identity to e-maxx: cur_abs = C[i0-1][j-1] - u_s[i0] - v_s[j] + D, M=minv+D.
    int p_final = 0;
    int wave = tid >> 6;
    int lane = tid & 63;
    if (tid < 128) {
        int b = wave;
        int j = lane;
        bool valid = (j >= 1 && j <= PB);
        float u_reg = 0.f;              // lane r: u[r+1]
        float v_reg = 0.f;              // lane j: v[j]
        int   p_reg = 0;                // lane j: p[j]; lane 0 = virtual column 0

        for (int i = 1; i <= GB; ++i) {
            float Mv = 3e38f;
            int   way_reg = 0;
            bool  used = (lane == 0);   // virtual col 0 used from start, Duse=0
            float Duse = 0.f;
            if (lane == 0) p_reg = i;
            if (lane < GB) uincr[b][lane] = 0.f;
            int j0 = 0;
            float D = 0.f;
            for (int it = 0; it < 2*PB + 4; ++it) {
                int i0 = __builtin_amdgcn_readlane(p_reg, j0);
                float u0 = __int_as_float(__builtin_amdgcn_readlane(__float_as_int(u_reg), i0 - 1));
                float Crow = valid ? Ct[b][i0-1][j-1] : 0.f;
                float cur = Crow - u0 - v_reg + D;
                if (valid && !used && cur < Mv) { Mv = cur; way_reg = j0; }
                float cand = (valid && !used) ? Mv : 3e38f;
                float dm = wave_min64(cand);
                unsigned long long msk = __ballot(cand == dm);
                int j1 = (int)__ffsll(msk) - 1;
                D = dm;
                if (lane == j1) { used = true; Duse = dm; }
                j0 = j1;
                int pj0 = __builtin_amdgcn_readlane(p_reg, j0);
                if (pj0 == 0) break;
            }
            // dual updates (before augment): used columns got every delta since use
            if (used) {
                v_reg -= (D - Duse);               // lane 0's v is a dummy
                uincr[b][p_reg - 1] = D - Duse;    // distinct rows per used column
            }
            // augment along way[] (uniform chain, readlane)
            int jj = j0;
            for (int g2 = 0; g2 < PB + 2 && jj; ++g2) {
                int j1 = __builtin_amdgcn_readlane(way_reg, jj);
                int pj1 = __builtin_amdgcn_readlane(p_reg, j1);
                if (lane == jj) p_reg = pj1;
                jj = j1;
            }
            if (lane < GB) u_reg += uincr[b][lane];
        }
        p_final = p_reg;

        // per-batch loss components (double for exact final sums)
        double nvbd = (double)nvbs[b];
        double myb = 0.0, myd = 0.0, myf = 0.0, myu = 0.0;
        if (valid) {
            int pj = p_final;
            int p = j - 1;
            if (pj > 0) {
                int ii = pj - 1;
                myb = ((double)tneg[b][p] - (double)fs2[b*GB + ii][0][p]) / nvbd;
                myd = 1.0 - (2.0*(double)fs2[b*GB + ii][1][p] + 1.0) /
                            ((double)tsig[b][p] + (double)cntf[b*GB + ii] + 1.0);
            } else {
                myf = (double)tfoc[b][p];
                myu = 1.0;
            }
        }
        #pragma unroll
        for (int off = 32; off >= 1; off >>= 1) {
            myb += __shfl_xor(myb, off);
            myd += __shfl_xor(myd, off);
            myf += __shfl_xor(myf, off);
            myu += __shfl_xor(myu, off);
        }
        if (lane == 0) {
            double G = (double)GB;
            double bce  = 2.0 * myb / G;                                  // L_B = 2
            double dice = 1.0 * myd / G;                                  // L_D = 1
            double unm  = (myu > 0.0) ? 7.0 * 0.75 * myf / (myu * nvbd)   // L_U, alpha
                                      : 0.0;
            bres[b][0] = bce; bres[b][1] = dice; bres[b][2] = unm;
        }
    }
    __syncthreads();

    if (tid == 0) {
        double L[5] = {0,0,0,0,0};
        for (int b = 0; b < 2; ++b) {
            double bce = bres[b][0], dice = bres[b][1], unm = bres[b][2];
            double matched = bce + dice;
            double total = matched + unm;
            L[0] += total; L[1] += matched; L[2] += unm; L[3] += bce; L[4] += dice;
        }
        for (int k2 = 0; k2 < 5; ++k2) outp[k2] = (float)(L[k2] / 2.0);
    }
}

extern "C" void kernel_launch(void* const* d_in, const int* in_sizes, int n_in,
                              void* d_out, int out_size, void* d_ws, size_t ws_size,
                              hipStream_t stream)
{
    const float* logits = (const float*)d_in[0];
    const int* gi = (const int*)d_in[2];
    int NV = in_sizes[1];

    int* wsi = (int*)d_ws;
    int* counts = wsi;                       // 48*256
    int* offs   = counts + NBUK * NH;        // 48*256
    int* bs     = offs + NBUK * NH;          // 64
    int* sidx   = bs + 64;                   // NV
    float* partials = (float*)(sidx + NV);   // 768*160

    hipLaunchKernelGGL(k_hist,    dim3(NH), dim3(256), 0, stream, gi, NV, counts);
    hipLaunchKernelGGL(k_scan,    dim3(1), dim3(1024), 0, stream, counts, offs, bs);
    hipLaunchKernelGGL(k_scatter, dim3(NH), dim3(256), 0, stream, gi, NV, offs, sidx);
    hipLaunchKernelGGL(k_accum2,  dim3(NBUK * SL), dim3(256), 0, stream, logits, sidx, bs, partials);
    hipLaunchKernelGGL(k_final,   dim3(1), dim3(1024), 0, stream, partials, bs, (float*)d_out);
}